// Round 7
// baseline (197.899 us; speedup 1.0000x reference)
//
#include <hip/hip_runtime.h>

// VQ-VAE forward: N=131072 rows (D=64), K=512 codes.
// Outputs flat: [loss(1) | quantized_st(8388608, NCHW) | perplexity(1) | encodings(131072x512)]
//
// R7: 8x8 register tile (was 4x4). R6 counters showed LDS-throughput-bound: 2 B/FMA * 4.3G FMA
// = 8.4 GB LDS traffic ~ 160us. 8x8 halves bytes/FMA to 1.0 -> ~82us LDS floor, 55us FMA floor.
// Per-cell accumulation stays single-acc over d ascending == bit-identical distances to R6
// (validated absmax 0.0) -> argmin unchanged.
// Also fixed from R6 counters: zero-fill now contiguous full-line wave-stores (WRITE_SIZE was
// 531MB from 64B@256B-stride partial lines; expect ~305MB); eT staged row-read/column-write
// (2-way banks, was 8-way scatter = 2.45M conflicts).

#define OFF_Q    1
#define OFF_PERP 8388609
#define OFF_ENC  8388610
#define EPAD 516

__global__ __launch_bounds__(512) void vq_prep(const float* __restrict__ emb,
                                               float* __restrict__ Bk,
                                               unsigned* __restrict__ counts,
                                               unsigned long long* __restrict__ lossAcc) {
    int k = threadIdx.x;  // 512 threads, one per code
    const float4* e4 = reinterpret_cast<const float4*>(emb) + k * 16;
    float s = 0.f;
    #pragma unroll
    for (int i = 0; i < 16; ++i) {
        float4 v = e4[i];
        s += v.x * v.x + v.y * v.y + v.z * v.z + v.w * v.w;
    }
    Bk[k] = s;
    counts[k] = 0u;
    if (k == 0) *lossAcc = 0ull;
}

__global__ __launch_bounds__(512, 1) void vq_main(const float* __restrict__ in,
                                                  const float* __restrict__ emb,
                                                  const float* __restrict__ Bk,
                                                  unsigned* __restrict__ counts,
                                                  unsigned long long* __restrict__ lossAcc,
                                                  float* __restrict__ out) {
    __shared__ float eT[64 * EPAD];   // e transposed: eT[d][k]     132096 B
    __shared__ float xT[64 * 64];     // x transposed: xT[c][row]    16384 B
    __shared__ float Bh[512];         // ||e_k||^2                    2048 B
    __shared__ float Ap[8][64];       // per-wave ||x||^2 partials    2048 B
    __shared__ float sdw[8][64];      // per-wave best dist           2048 B
    __shared__ int   skw[8][64];      // per-wave best k              2048 B

    const int tid  = (int)threadIdx.x;
    const int lane = tid & 63;
    const int v    = __builtin_amdgcn_readfirstlane(tid >> 6);  // wave 0..7 (uniform)
    const int rq   = lane >> 3;       // row-octet: rows rq*8 .. rq*8+7
    const int cq   = lane & 7;        // code-octet within wave's 64 codes

    // ---- stage eT (row-read, column-write: 2-way banks) + Bh ----
    {
        const float4* myrow = reinterpret_cast<const float4*>(emb) + (size_t)tid * 16;
        #pragma unroll
        for (int i = 0; i < 16; ++i) {
            float4 r = myrow[i];
            eT[(i * 4 + 0) * EPAD + tid] = r.x;
            eT[(i * 4 + 1) * EPAD + tid] = r.y;
            eT[(i * 4 + 2) * EPAD + tid] = r.z;
            eT[(i * 4 + 3) * EPAD + tid] = r.w;
        }
        Bh[tid] = Bk[tid];
    }
    // (visibility covered by group-0's barrier1)

    float lacc = 0.f;

    for (int g = 0; g < 8; ++g) {
        const int gab = (int)blockIdx.x * 8 + g;   // row-group 0..2047 = b*64+h
        const int bb  = gab >> 6;
        const int hh  = gab & 63;
        const size_t rowBase = (size_t)bb * 262144 + (size_t)hh * 64 + (size_t)lane;

        // ---- stage x tile transposed; wave v loads channels [v*8, v*8+8) ----
        float asum = 0.f;
        #pragma unroll
        for (int cc = 0; cc < 8; ++cc) {
            int c = v * 8 + cc;
            float val = in[rowBase + (size_t)c * 4096];
            xT[c * 64 + lane] = val;
            asum += val * val;
        }
        Ap[v][lane] = asum;
        __syncthreads();   // barrier1: eT (g=0) + xT + Ap staged

        // ---- zero-fill burst: contiguous full-line wave-stores, fire-and-forget ----
        // slab byte base is 8-mod-16 -> float2 (each instr: 512 thr x 8B contiguous)
        {
            float2* zb2 = reinterpret_cast<float2*>(out + OFF_ENC + (size_t)gab * 32768);
            const float2 z2 = make_float2(0.f, 0.f);
            #pragma unroll
            for (int z = 0; z < 32; ++z) zb2[z * 512 + tid] = z2;
        }

        // ---- 8x8 outer-product d-loop: 4x ds_read_b128 -> 64 FMA per d ----
        const float* xbase = &xT[rq * 8];
        const float* ebase = &eT[v * 64 + cq * 8];
        float acc[8][8];
        #pragma unroll
        for (int i = 0; i < 8; ++i)
            #pragma unroll
            for (int j = 0; j < 8; ++j) acc[i][j] = 0.f;

        #pragma unroll 4
        for (int d = 0; d < 64; ++d) {
            const float4 x0 = *reinterpret_cast<const float4*>(xbase + d * 64);
            const float4 x1 = *reinterpret_cast<const float4*>(xbase + d * 64 + 4);
            const float4 e0 = *reinterpret_cast<const float4*>(ebase + (size_t)d * EPAD);
            const float4 e1 = *reinterpret_cast<const float4*>(ebase + (size_t)d * EPAD + 4);
            const float xs[8] = {x0.x, x0.y, x0.z, x0.w, x1.x, x1.y, x1.z, x1.w};
            const float es[8] = {e0.x, e0.y, e0.z, e0.w, e1.x, e1.y, e1.z, e1.w};
            #pragma unroll
            for (int i = 0; i < 8; ++i)
                #pragma unroll
                for (int j = 0; j < 8; ++j)
                    acc[i][j] += xs[i] * es[j];   // single-acc per cell, d ascending (== R6 order)
        }

        // ---- ||x||^2 for my 8 rows (broadcast reads, 2-way banks) ----
        float Af[8];
        #pragma unroll
        for (int i = 0; i < 8; ++i) {
            float s = 0.f;
            #pragma unroll
            for (int vv = 0; vv < 8; ++vv) s += Ap[vv][rq * 8 + i];
            Af[i] = s;
        }

        // ---- dist + per-lane argmin over its 8 codes (j ascending = k ascending) ----
        const int kb0 = v * 64 + cq * 8;
        const float4 bv0 = *reinterpret_cast<const float4*>(&Bh[kb0]);
        const float4 bv1 = *reinterpret_cast<const float4*>(&Bh[kb0 + 4]);
        const float bs[8] = {bv0.x, bv0.y, bv0.z, bv0.w, bv1.x, bv1.y, bv1.z, bv1.w};
        float bd[8];
        int   bk[8];
        #pragma unroll
        for (int i = 0; i < 8; ++i) {
            bd[i] = 3.4e38f; bk[i] = kb0;
            #pragma unroll
            for (int j = 0; j < 8; ++j) {
                float di = (Af[i] + bs[j]) - 2.0f * acc[i][j];   // reference op order
                if (di < bd[i]) { bd[i] = di; bk[i] = kb0 + j; } // strict < = first-min
            }
        }

        // ---- reduce across the 8 cq lanes of each row-octet (tie -> lower k) ----
        #pragma unroll
        for (int i = 0; i < 8; ++i) {
            #pragma unroll
            for (int s = 1; s < 8; s <<= 1) {
                float od = __shfl_xor(bd[i], s);
                int   ok = __shfl_xor(bk[i], s);
                if (od < bd[i] || (od == bd[i] && ok < bk[i])) { bd[i] = od; bk[i] = ok; }
            }
        }
        // lane rq*8+cq owns row rq*8+cq -> select element cq (static select chain)
        const float myd = (cq < 4) ? ((cq < 2) ? (cq == 0 ? bd[0] : bd[1]) : (cq == 2 ? bd[2] : bd[3]))
                                   : ((cq < 6) ? (cq == 4 ? bd[4] : bd[5]) : (cq == 6 ? bd[6] : bd[7]));
        const int   myk = (cq < 4) ? ((cq < 2) ? (cq == 0 ? bk[0] : bk[1]) : (cq == 2 ? bk[2] : bk[3]))
                                   : ((cq < 6) ? (cq == 4 ? bk[4] : bk[5]) : (cq == 6 ? bk[6] : bk[7]));
        sdw[v][lane] = myd;
        skw[v][lane] = myk;
        __syncthreads();   // barrier2: argmins shared

        // ---- final argmin across waves (v ascending == k-range ascending; strict <) ----
        float fd = sdw[0][lane];
        int   fk = skw[0][lane];
        #pragma unroll
        for (int vv = 1; vv < 8; ++vv) {
            const float dv = sdw[vv][lane];
            const int   kv = skw[vv][lane];
            if (dv < fd) { fd = dv; fk = kv; }
        }

        // ---- epilogue: wave v writes channels [v*8, v*8+8) for all 64 rows (lane = row) ----
        #pragma unroll
        for (int cc = 0; cc < 8; ++cc) {
            const int c = v * 8 + cc;
            const float xv = xT[c * 64 + lane];
            const float q  = eT[c * EPAD + fk];
            const float dd = q - xv;
            lacc += dd * dd;
            out[OFF_Q + rowBase + (size_t)c * 4096] = xv + dd;   // x + (q - x), ref order
        }
        __syncthreads();   // barrier3: protects xT for next group AND drains all stores
                           // (vmcnt(0) before s_barrier) => one-hot scatter is safe

        if (v == 0) {
            atomicAdd(&counts[fk], 1u);
            out[OFF_ENC + (size_t)gab * 32768 + (size_t)lane * 512 + (size_t)fk] = 1.0f;
        }
    }

    // deterministic loss accumulation (fixed-point, validated R1-R6)
    #pragma unroll
    for (int off = 32; off > 0; off >>= 1) lacc += __shfl_down(lacc, off);
    if (lane == 0) {
        unsigned long long fx = (unsigned long long)((double)lacc * 1048576.0);
        atomicAdd(lossAcc, fx);
    }
}

__global__ __launch_bounds__(512) void vq_fin(const unsigned* __restrict__ counts,
                                              const unsigned long long* __restrict__ lossAcc,
                                              float* __restrict__ out) {
    __shared__ float red[512];
    int k = threadIdx.x;
    float p = (float)counts[k] * (1.0f / 131072.0f);  // exact: count * 2^-17
    red[k] = p * logf(p + 1e-10f);
    __syncthreads();
    for (int s = 256; s > 0; s >>= 1) {
        if (k < s) red[k] += red[k + s];
        __syncthreads();
    }
    if (k == 0) {
        out[OFF_PERP] = expf(-red[0]);
        double m = ((double)(*lossAcc) / 1048576.0) / 8388608.0;
        float mf = (float)m;
        out[0] = mf + 0.25f * mf;  // q_latent + 0.25 * e_latent (identical values)
    }
}

extern "C" void kernel_launch(void* const* d_in, const int* in_sizes, int n_in,
                              void* d_out, int out_size, void* d_ws, size_t ws_size,
                              hipStream_t stream) {
    const float* in  = (const float*)d_in[0];
    // d_in[1] = labels (unused by the reference forward)
    const float* emb = (const float*)d_in[2];
    float* out = (float*)d_out;

    float* Bk                    = (float*)d_ws;                              // 512 f32
    unsigned* counts             = (unsigned*)((char*)d_ws + 2048);           // 512 u32
    unsigned long long* lossAcc  = (unsigned long long*)((char*)d_ws + 4096); // 1 u64

    vq_prep<<<1, 512, 0, stream>>>(emb, Bk, counts, lossAcc);
    vq_main<<<256, 512, 0, stream>>>(in, emb, Bk, counts, lossAcc, out);
    vq_fin<<<1, 512, 0, stream>>>(counts, lossAcc, out);
}